// Round 6
// baseline (10050.271 us; speedup 1.0000x reference)
//
#include <hip/hip_runtime.h>

typedef unsigned short US;
typedef unsigned int   UI;
typedef __bf16 bf16x8 __attribute__((ext_vector_type(8)));
typedef float  f32x4  __attribute__((ext_vector_type(4)));

#define BB 64
#define AA 128
#define HH 512
#define TT 64
#define VV 32000

// ---------- helpers ----------
__device__ __forceinline__ US f2bf(float f) {
  UI u = __builtin_bit_cast(UI, f);
  UI r = (u + 0x7fffu + ((u >> 16) & 1u)) >> 16;   // RNE, finite inputs
  return (US)r;
}
__device__ __forceinline__ float bflo(UI u){ return __builtin_bit_cast(float, u << 16); }
__device__ __forceinline__ float bfhi(UI u){ return __builtin_bit_cast(float, u & 0xffff0000u); }

__device__ __forceinline__ float dot8(uint4 w, const float* __restrict__ x){
  float a = 0.f;
  a += x[0]*bflo(w.x); a += x[1]*bfhi(w.x);
  a += x[2]*bflo(w.y); a += x[3]*bfhi(w.y);
  a += x[4]*bflo(w.z); a += x[5]*bfhi(w.z);
  a += x[6]*bflo(w.w); a += x[7]*bfhi(w.w);
  return a;
}

// ---------- small prep kernels ----------
__global__ void copy_f(float* o, const float* i, int n){
  int x = blockIdx.x*blockDim.x + threadIdx.x; if (x < n) o[x] = i[x];
}
__global__ void cast4_k(US* o, const float* in, int n4){
  int x = blockIdx.x*blockDim.x + threadIdx.x;
  if (x < n4){
    float4 v = ((const float4*)in)[x];
    ushort4 r; r.x=f2bf(v.x); r.y=f2bf(v.y); r.z=f2bf(v.z); r.w=f2bf(v.w);
    ((ushort4*)o)[x] = r;
  }
}
// out[r*C + c] = bf16( in[c*in_stride + r] )   (R,C multiples of 32)
__global__ void tcast_k(US* __restrict__ out, const float* __restrict__ in,
                        int R, int C, int in_stride){
  __shared__ float tile[32][33];
  int r0 = blockIdx.x*32, c0 = blockIdx.y*32;
  int tx = threadIdx.x, ty = threadIdx.y;  // (32,8)
  #pragma unroll
  for (int k=0;k<4;k++)
    tile[tx][ty+8*k] = in[(long)(c0+ty+8*k)*in_stride + r0 + tx];
  __syncthreads();
  #pragma unroll
  for (int k=0;k<4;k++)
    out[(long)(r0+ty+8*k)*C + c0 + tx] = f2bf(tile[ty+8*k][tx]);
}
// W2gT[j2*256 + j] = sum_n Wf2[j,n] * Wg1[512+n, j2]
__global__ void w2g_k(US* __restrict__ W2gT, const float* __restrict__ Wf2,
                      const float* __restrict__ Wg1){
  int j2 = blockIdx.x, j = threadIdx.x;
  float a = 0.f;
  for (int n=0;n<HH;n++) a += Wf2[j*HH + n] * Wg1[(512+n)*256 + j2];
  W2gT[j2*256 + j] = f2bf(a);
}
// bg1p[j2] = Wg1_b[j2] + sum_n Wf2_b[n]*Wg1[512+n, j2]
__global__ void bg1p_k(float* out, const float* Wg1_b, const float* Wf2_b,
                       const float* Wg1){
  int j2 = threadIdx.x;
  float a = Wg1_b[j2];
  for (int n=0;n<HH;n++) a += Wf2_b[n]*Wg1[(512+n)*256 + j2];
  out[j2] = a;
}

// ---------- bf16 MFMA GEMM: C[M,N] = A[M,K] @ Bt[N,K]^T (+bias[col]) ----------
template<int OUT_BF16>
__global__ __launch_bounds__(256) void gemm_bt(
    const US* __restrict__ A, const US* __restrict__ Bt, void* __restrict__ Cv,
    const float* __restrict__ bias, int M, int N, int K,
    long Az, long Bz, long Cz)
{
  const long zb = blockIdx.z;
  A  += zb*Az;  Bt += zb*Bz;
  __shared__ __align__(16) US lA[128*64];
  __shared__ __align__(16) US lB[128*64];
  const int tid = threadIdx.x, lane = tid & 63, w = tid >> 6;
  const int wr = w >> 1, wc = w & 1;
  const int tm = blockIdx.x, tn = blockIdx.y;
  f32x4 acc[4][4] = {};
  for (int kt = 0; kt < K; kt += 64) {
    __syncthreads();
    #pragma unroll
    for (int i=0;i<4;i++){
      int ci = tid + 256*i; int r = ci>>3, o = (ci&7)*8;
      *(uint4*)&lA[r*64+o] = *(const uint4*)&A [(long)(tm*128+r)*K + kt + o];
      *(uint4*)&lB[r*64+o] = *(const uint4*)&Bt[(long)(tn*128+r)*K + kt + o];
    }
    __syncthreads();
    #pragma unroll
    for (int ks=0; ks<2; ++ks){
      bf16x8 af[4], bfr[4];
      #pragma unroll
      for(int m=0;m<4;m++){
        uint4 t = *(const uint4*)&lA[(wr*64+m*16+(lane&15))*64 + ks*32 + (lane>>4)*8];
        af[m] = __builtin_bit_cast(bf16x8, t);
      }
      #pragma unroll
      for(int n=0;n<4;n++){
        uint4 t = *(const uint4*)&lB[(wc*64+n*16+(lane&15))*64 + ks*32 + (lane>>4)*8];
        bfr[n] = __builtin_bit_cast(bf16x8, t);
      }
      #pragma unroll
      for(int m=0;m<4;m++)
        #pragma unroll
        for(int n=0;n<4;n++)
          acc[m][n] = __builtin_amdgcn_mfma_f32_16x16x32_bf16(af[m], bfr[n], acc[m][n], 0,0,0);
    }
  }
  #pragma unroll
  for(int m=0;m<4;m++){
    #pragma unroll
    for(int n=0;n<4;n++){
      const int col = tn*128 + wc*64 + n*16 + (lane&15);
      const float bv = bias ? bias[col] : 0.f;
      #pragma unroll
      for(int r=0;r<4;r++){
        const int row = tm*128 + wr*64 + m*16 + (lane>>4)*4 + r;
        const float v = acc[m][n][r] + bv;
        if (OUT_BF16) ((US*)Cv)  [zb*Cz + (long)row*N + col] = f2bf(v);
        else          ((float*)Cv)[zb*Cz + (long)row*N + col] = v;
      }
    }
  }
}

// ---------- inter-block barrier (4 blocks per batch row, monotonic counter) ----------
__device__ __forceinline__ void bbar(int* cnt, int target){
  __syncthreads();
  if (threadIdx.x == 0){
    __threadfence();
    __hip_atomic_fetch_add(cnt, 1, __ATOMIC_RELEASE, __HIP_MEMORY_SCOPE_AGENT);
    while (__hip_atomic_load(cnt, __ATOMIC_ACQUIRE, __HIP_MEMORY_SCOPE_AGENT) < target)
      __builtin_amdgcn_s_sleep(2);
  }
  __syncthreads();
}

// ---------- fused 64-step decoder scan: 4 blocks per batch row ----------
__global__ __launch_bounds__(512) void scan_k(
  float* __restrict__ S, float* __restrict__ Y, float* __restrict__ TMP,
  float* __restrict__ E, float* __restrict__ U, float* __restrict__ V,
  int* __restrict__ cnt,
  const US* __restrict__ Wa1sT, const US* __restrict__ Wg2T,
  const US* __restrict__ annproj, const US* __restrict__ annFt, const US* __restrict__ annGt,
  const US* __restrict__ Wf1syT, const US* __restrict__ Wf2T,
  const US* __restrict__ Wg1yT, const US* __restrict__ W2gT,
  const float* __restrict__ bg1p, const float* __restrict__ wa2g,
  const float* __restrict__ Wf1_b, const float* __restrict__ Wf2_b,
  const float* __restrict__ Wg2_b,
  US* __restrict__ ys)
{
  const int b = blockIdx.x & 63, q = blockIdx.x >> 6;
  const int tid = threadIdx.x;
  __shared__ float s_l[512], y_l[512], tmp_l[512], v_l[256], u_l[256];
  __shared__ float p_l[128], aF_l[64], aG_l[64], wa2[512], red_l[4];
  wa2[tid] = wa2g[tid];
  float* Sb = S + b*512;  float* Yb = Y + b*512;  float* Tb = TMP + b*512;
  float* Eb = E + b*128;  float* Ub = U + b*256;  float* Vb = V + b*256;
  int* cb = cnt + b*32;           // 128B-strided counters, no false sharing
  int bt = 0;

  for (int t = 0; t <= TT; ++t) {
    // ---- X1: y_t = v_{t-1}@Wg2 + bg2 ; tmp = s_t@Wa1_s ----
    if (t > 0 && tid < 256) v_l[tid] = Vb[tid];
    s_l[tid] = Sb[tid];
    __syncthreads();
    {
      const int n_loc = tid >> 2, kq = tid & 3;
      const int n = q*128 + n_loc;
      if (t > 0) {
        const US* wrow = Wg2T + n*256 + kq*64;
        const float* x = &v_l[kq*64];
        float p = 0.f;
        #pragma unroll
        for (int i=0;i<8;i++) p += dot8(*(const uint4*)&wrow[i*8], &x[i*8]);
        p += __shfl_xor(p, 1); p += __shfl_xor(p, 2);
        if (kq == 0) {
          float yv = p + Wg2_b[n];
          Yb[n] = yv;
          ys[((long)b*TT + (t-1))*512 + n] = f2bf(yv);
        }
      }
      if (t == TT) break;
      {
        const US* wrow = Wa1sT + n*512 + kq*128;
        const float* x = &s_l[kq*128];
        float p = 0.f;
        #pragma unroll
        for (int i=0;i<16;i++) p += dot8(*(const uint4*)&wrow[i*8], &x[i*8]);
        p += __shfl_xor(p, 1); p += __shfl_xor(p, 2);
        if (kq == 0) Tb[n] = p;
      }
    }
    bt += 4; bbar(cb, bt);

    // ---- X2: e[a] = sum_h relu(tmp[h]+ann_proj[b,a,h]) * wa2[h] ----
    tmp_l[tid] = Tb[tid];
    __syncthreads();
    {
      const int a_loc = tid >> 4, hq = tid & 15;
      const int a = q*32 + a_loc;
      const US* prow = annproj + ((long)b*AA + a)*512 + hq*32;
      float p = 0.f;
      #pragma unroll
      for (int i=0;i<4;i++){
        uint4 wv = *(const uint4*)&prow[i*8];
        const int h = hq*32 + i*8;
        float tv;
        tv = tmp_l[h+0]+bflo(wv.x); p += fmaxf(tv,0.f)*wa2[h+0];
        tv = tmp_l[h+1]+bfhi(wv.x); p += fmaxf(tv,0.f)*wa2[h+1];
        tv = tmp_l[h+2]+bflo(wv.y); p += fmaxf(tv,0.f)*wa2[h+2];
        tv = tmp_l[h+3]+bfhi(wv.y); p += fmaxf(tv,0.f)*wa2[h+3];
        tv = tmp_l[h+4]+bflo(wv.z); p += fmaxf(tv,0.f)*wa2[h+4];
        tv = tmp_l[h+5]+bfhi(wv.z); p += fmaxf(tv,0.f)*wa2[h+5];
        tv = tmp_l[h+6]+bflo(wv.w); p += fmaxf(tv,0.f)*wa2[h+6];
        tv = tmp_l[h+7]+bfhi(wv.w); p += fmaxf(tv,0.f)*wa2[h+7];
      }
      p += __shfl_xor(p,1); p += __shfl_xor(p,2); p += __shfl_xor(p,4); p += __shfl_xor(p,8);
      if (hq == 0) Eb[a] = p;
    }
    bt += 4; bbar(cb, bt);

    // ---- X3/X4: softmax ; attnF/attnG ; u = relu([s,y]@Wf1_sy + attnF + bf1) ----
    float ev = -1e30f;
    if (tid < 128){ ev = Eb[tid]; p_l[tid] = ev; }
    y_l[tid] = Yb[tid];
    __syncthreads();
    float mloc = ev;
    #pragma unroll
    for (int o=32;o;o>>=1) mloc = fmaxf(mloc, __shfl_xor(mloc,o));
    if (tid==0)  red_l[0]=mloc;
    if (tid==64) red_l[1]=mloc;
    __syncthreads();
    const float mx = fmaxf(red_l[0], red_l[1]);
    float dloc = 0.f;
    if (tid < 128){ float pe = expf(ev - mx); p_l[tid] = pe; dloc = pe; }
    #pragma unroll
    for (int o=32;o;o>>=1) dloc += __shfl_xor(dloc,o);
    if (tid==0)  red_l[2]=dloc;
    if (tid==64) red_l[3]=dloc;
    __syncthreads();
    const float dinv = 1.f/(red_l[2]+red_l[3]);
    {
      const int j_loc = tid>>3, aq = tid&7;
      const int j = q*64 + j_loc;
      const US* fr = annFt + ((long)b*256 + j)*AA + aq*16;
      const US* gr = annGt + ((long)b*256 + j)*AA + aq*16;
      float pF=0.f, pG=0.f;
      #pragma unroll
      for (int i=0;i<2;i++){
        pF += dot8(*(const uint4*)&fr[i*8], &p_l[aq*16 + i*8]);
        pG += dot8(*(const uint4*)&gr[i*8], &p_l[aq*16 + i*8]);
      }
      pF += __shfl_xor(pF,1); pF += __shfl_xor(pF,2); pF += __shfl_xor(pF,4);
      pG += __shfl_xor(pG,1); pG += __shfl_xor(pG,2); pG += __shfl_xor(pG,4);
      if (aq==0){ aF_l[j_loc]=pF; aG_l[j_loc]=pG; }
    }
    __syncthreads();
    {
      const int j_loc = tid>>3, kq = tid&7;
      const int j = q*64 + j_loc;
      const US* wrow = Wf1syT + (long)j*1024 + kq*128;
      float p = 0.f;
      #pragma unroll
      for (int i=0;i<16;i++){
        const int k = kq*128 + i*8;
        const float* x = (k < 512) ? &s_l[k] : &y_l[k-512];
        p += dot8(*(const uint4*)&wrow[i*8], x);
      }
      p += __shfl_xor(p,1); p += __shfl_xor(p,2); p += __shfl_xor(p,4);
      if (kq==0) Ub[j] = fmaxf(p + aF_l[j_loc]*dinv + Wf1_b[j], 0.f);
    }
    bt += 4; bbar(cb, bt);

    // ---- X5: s_{t+1} = u@Wf2 + bf2 ; v = relu(y@Wg1_y + u@W2g + attnG + bg1') ----
    if (tid < 256) u_l[tid] = Ub[tid];
    __syncthreads();
    {
      const int n_loc = tid>>2, kq = tid&3;
      const int n = q*128 + n_loc;
      const US* wrow = Wf2T + n*256 + kq*64;
      const float* x = &u_l[kq*64];
      float p = 0.f;
      #pragma unroll
      for (int i=0;i<8;i++) p += dot8(*(const uint4*)&wrow[i*8], &x[i*8]);
      p += __shfl_xor(p,1); p += __shfl_xor(p,2);
      if (kq==0) Sb[n] = p + Wf2_b[n];
    }
    {
      const int j2_loc = tid>>3, kq = tid&7;
      const int j2 = q*64 + j2_loc;
      const US* wy = Wg1yT + (long)j2*512 + kq*64;
      const US* wu = W2gT + j2*256 + kq*32;
      float p = 0.f;
      #pragma unroll
      for (int i=0;i<8;i++) p += dot8(*(const uint4*)&wy[i*8], &y_l[kq*64 + i*8]);
      #pragma unroll
      for (int i=0;i<4;i++) p += dot8(*(const uint4*)&wu[i*8], &u_l[kq*32 + i*8]);
      p += __shfl_xor(p,1); p += __shfl_xor(p,2); p += __shfl_xor(p,4);
      if (kq==0) Vb[j2] = fmaxf(p + aG_l[j2_loc]*dinv + bg1p[j2], 0.f);
    }
    bt += 4; bbar(cb, bt);
  }
}

// ---------- host ----------
extern "C" void kernel_launch(void* const* d_in, const int* in_sizes, int n_in,
                              void* d_out, int out_size, void* d_ws, size_t ws_size,
                              hipStream_t stream)
{
  (void)in_sizes; (void)n_in; (void)out_size; (void)ws_size;
  const float* hidden = (const float*)d_in[0];
  const float* ann    = (const float*)d_in[1];
  const float* Wa1_w  = (const float*)d_in[2];
  const float* Wa1_b  = (const float*)d_in[3];
  const float* Wa2_w  = (const float*)d_in[4];
  const float* Wf1_w  = (const float*)d_in[6];
  const float* Wf1_b  = (const float*)d_in[7];
  const float* Wf2_w  = (const float*)d_in[8];
  const float* Wf2_b  = (const float*)d_in[9];
  const float* Wg1_w  = (const float*)d_in[10];
  const float* Wg1_b  = (const float*)d_in[11];
  const float* Wg2_w  = (const float*)d_in[12];
  const float* Wg2_b  = (const float*)d_in[13];
  const float* fc_w   = (const float*)d_in[14];
  const float* fc_b   = (const float*)d_in[15];

  char* ws = (char*)d_ws;
  size_t off = 0;
  auto alloc = [&](size_t bytes)->char*{ char* p = ws + off; off += (bytes + 255) & ~255ULL; return p; };
  int*   cnt   = (int*)  alloc(64*32*4);        // barrier counters (zeroed)
  float* Y     = (float*)alloc(64*512*4);       // zeroed (y0 = 0)
  float* S     = (float*)alloc(64*512*4);
  float* TMP   = (float*)alloc(64*512*4);
  float* E     = (float*)alloc(64*128*4);
  float* U     = (float*)alloc(64*256*4);
  float* V     = (float*)alloc(64*256*4);
  float* BG1P  = (float*)alloc(256*4);
  US* Wa1sT  = (US*)alloc(512*512*2);
  US* WannT  = (US*)alloc(512*1024*2);
  US* Wf1cT  = (US*)alloc(256*1024*2);
  US* Wg1cT  = (US*)alloc(256*1024*2);
  US* Wf1syT = (US*)alloc(256*1024*2);
  US* Wf2T   = (US*)alloc(512*256*2);
  US* Wg1yT  = (US*)alloc(256*512*2);
  US* Wg2T   = (US*)alloc(512*256*2);
  US* W2gT   = (US*)alloc(256*256*2);
  US* annbf  = (US*)alloc((size_t)64*128*1024*2);
  US* annproj= (US*)alloc((size_t)64*128*512*2);
  US* annFt  = (US*)alloc((size_t)64*256*128*2);
  US* annGt  = (US*)alloc((size_t)64*256*128*2);
  US* ysbf   = (US*)alloc((size_t)64*64*512*2);
  US* fcwT   = (US*)alloc((size_t)32000*512*2);

  hipMemsetAsync(d_ws, 0, 64*32*4 + 64*512*4, stream);   // cnt + Y (contiguous)
  copy_f<<<64, 512, 0, stream>>>(S, hidden, 64*512);
  cast4_k<<<8192, 256, 0, stream>>>(annbf, ann, 64*128*1024/4);

  dim3 tb(32,8);
  tcast_k<<<dim3(16,16),  tb, 0, stream>>>(Wa1sT,  Wa1_w,            512, 512,  512);
  tcast_k<<<dim3(16,32),  tb, 0, stream>>>(WannT,  Wa1_w + 512*512,  512, 1024, 512);
  tcast_k<<<dim3(8,32),   tb, 0, stream>>>(Wf1cT,  Wf1_w + 1024*256, 256, 1024, 256);
  tcast_k<<<dim3(8,32),   tb, 0, stream>>>(Wg1cT,  Wg1_w + 1024*256, 256, 1024, 256);
  tcast_k<<<dim3(8,32),   tb, 0, stream>>>(Wf1syT, Wf1_w,            256, 1024, 256);
  tcast_k<<<dim3(16,8),   tb, 0, stream>>>(Wf2T,   Wf2_w,            512, 256,  512);
  tcast_k<<<dim3(8,16),   tb, 0, stream>>>(Wg1yT,  Wg1_w,            256, 512,  256);
  tcast_k<<<dim3(16,8),   tb, 0, stream>>>(Wg2T,   Wg2_w,            512, 256,  512);
  tcast_k<<<dim3(1000,16),tb, 0, stream>>>(fcwT,   fc_w,           32000, 512, 32000);
  w2g_k<<<256, 256, 0, stream>>>(W2gT, Wf2_w, Wg1_w);
  bg1p_k<<<1, 256, 0, stream>>>(BG1P, Wg1_b, Wf2_b, Wg1_w);

  // ann_proj = ann @ Wa1_w[512:] + Wa1_b   (8192x512, K=1024)
  gemm_bt<1><<<dim3(64,4,1), 256, 0, stream>>>(annbf, WannT, annproj, Wa1_b,
                                               8192, 512, 1024, 0, 0, 0);
  // annFt[b] (256x128) = Wf1cT @ ann[b]^T ; annGt likewise
  gemm_bt<1><<<dim3(2,1,64), 256, 0, stream>>>(Wf1cT, annbf, annFt, nullptr,
                                               256, 128, 1024, 0, 128*1024, 256*128);
  gemm_bt<1><<<dim3(2,1,64), 256, 0, stream>>>(Wg1cT, annbf, annGt, nullptr,
                                               256, 128, 1024, 0, 128*1024, 256*128);

  scan_k<<<256, 512, 0, stream>>>(S, Y, TMP, E, U, V, cnt,
                                  Wa1sT, Wg2T, annproj, annFt, annGt,
                                  Wf1syT, Wf2T, Wg1yT, W2gT,
                                  BG1P, Wa2_w, Wf1_b, Wf2_b, Wg2_b, ysbf);

  // out (4096 x 32000) f32 = ys @ fc_w + fc_b
  gemm_bt<0><<<dim3(32,250,1), 256, 0, stream>>>(ysbf, fcwT, d_out, fc_b,
                                                 4096, 32000, 512, 0, 0, 0);
}